// Round 1
// baseline (1766.229 us; speedup 1.0000x reference)
//
#include <hip/hip_runtime.h>
#include <math.h>

// Problem constants (fixed by setup_inputs)
namespace {
constexpr int Bt = 4096;
constexpr int Nt = 32;       // tokens per batch
constexpr int Dm = 256;      // model dim = N_HEAD*D_K = N_HEAD*D_V
constexpr int DH = 128;      // half of Dm staged in LDS at a time
constexpr int NHEAD = 8;
constexpr float NEGV = -10000000000.0f;
constexpr int ATTN_BASE = Bt * Dm;            // normed is first in d_out
constexpr float INV_TEMP = 0.17677669529663687f;  // 1/sqrt(D_K)=1/sqrt(32)

// Type-selected projection over a d-half: acc[n] += sum_{d in half} xs[tokbase+n][d] * W[e][rowbase+d][j]
// tm[e] = bitmask (within this group's NTOK window) of tokens with type e (wave-uniform -> scalar branches).
template <int NTOK>
__device__ __forceinline__ void project_half(const float* __restrict__ W, int j,
                                             const unsigned* tm,
                                             const float (*xs)[DH], int rowbase,
                                             int tokbase, float* acc)
{
#pragma unroll
    for (int e = 0; e < 4; ++e) {
        unsigned m = tm[e];
        if (m == 0) continue;
        const float* We = W + e * (Dm * Dm) + rowbase * Dm + j;
        for (int d0 = 0; d0 < DH; d0 += 16) {
            float w[16];
#pragma unroll
            for (int dd = 0; dd < 16; ++dd) w[dd] = We[(d0 + dd) * Dm];
#pragma unroll
            for (int n = 0; n < NTOK; ++n) {
                if (m & (1u << n)) {   // uniform: s_and + s_cbranch, co-issues with VALU
#pragma unroll
                    for (int c = 0; c < 4; ++c) {
                        float4 xv = *(const float4*)&xs[tokbase + n][d0 + c * 4];
                        acc[n] = fmaf(xv.x, w[c * 4 + 0], acc[n]);
                        acc[n] = fmaf(xv.y, w[c * 4 + 1], acc[n]);
                        acc[n] = fmaf(xv.z, w[c * 4 + 2], acc[n]);
                        acc[n] = fmaf(xv.w, w[c * 4 + 3], acc[n]);
                    }
                }
            }
        }
    }
}
} // namespace

// 512 threads: warps 0-3 (grp=0) project Q, warps 4-7 (grp=1) project K.
// Peak live set ~56 VGPRs (one acc[32] per thread, roles disjoint) -> 8 waves/SIMD.
// LDS ~38 KB -> 4 blocks/CU -> 32 waves/CU = 100% occupancy.
__global__ __launch_bounds__(512, 8)
void mha_fused_kernel(const float* __restrict__ q, const float* __restrict__ k,
                      const float* __restrict__ v,
                      const float* __restrict__ Wq, const float* __restrict__ Wk,
                      const float* __restrict__ Wv,
                      const float* __restrict__ rel_pri,
                      const float* __restrict__ fc_w, const float* __restrict__ fc_b,
                      const float* __restrict__ gamma, const float* __restrict__ beta,
                      const int* __restrict__ seq_etype, const int* __restrict__ seq_utype,
                      const int* __restrict__ mask,
                      float* __restrict__ out)
{
    const int b = blockIdx.x;
    const int t = threadIdx.x;      // 0..511
    const int j = t & 255;          // output column 0..255
    const int grp = t >> 8;         // 0: Q-side, 1: K-side
    const int h = j >> 5;           // head
    const int l = j & 31;           // lane within head (== token index for softmax)

    __shared__ __align__(16) float smem[2 * Nt * DH];   // 32 KB: xsA | xsB; reused as Klds, then v staging
    __shared__ __align__(16) float outbuf[2][Dm];
    __shared__ __align__(16) float fcpart[2][Dm];
    __shared__ float attn_s[NHEAD][Nt];
    __shared__ float pri_s[Nt];
    __shared__ int   msks[Nt];
    __shared__ unsigned tmask_s[4];
    __shared__ int   ut_s;
    __shared__ float redA[4], redB[4];

    float (*xsA)[DH] = (float(*)[DH])smem;              // q (later v) half: 32 x 128
    float (*xsB)[DH] = (float(*)[DH])(smem + Nt * DH);  // k half: 32 x 128
    float (*Klds)[Dm] = (float(*)[Dm])smem;             // 32 x 256 at score time (aliases both)

    // ---- metadata ----
    if (t < 4) tmask_s[t] = 0u;
    if (t == 0) ut_s = seq_utype[b];
    __syncthreads();
    if (t < Nt) {
        int e = seq_etype[b * Nt + t];
        msks[t] = mask[b * Nt + t];
        pri_s[t] = rel_pri[ut_s * 4 + e] * INV_TEMP;
        atomicOr(&tmask_s[e], 1u << t);
    }
    __syncthreads();

    unsigned tm[4];
#pragma unroll
    for (int e = 0; e < 4; ++e) tm[e] = __builtin_amdgcn_readfirstlane(tmask_s[e]);
    const int ut = __builtin_amdgcn_readfirstlane(ut_s);

    // ---- Q (grp 0) / K (grp 1) projection over two d-halves ----
    const float4* sq = (const float4*)(q + (size_t)b * (Nt * Dm));
    const float4* sk = (const float4*)(k + (size_t)b * (Nt * Dm));
    float4* dA = (float4*)smem;
    float4* dB = dA + (Nt * DH / 4);

    const float* Wsel = grp ? Wk : Wq;
    const float (*xsel)[DH] = grp ? xsB : xsA;

    float acc[Nt];
#pragma unroll
    for (int n = 0; n < Nt; ++n) acc[n] = 0.f;

#pragma unroll
    for (int half = 0; half < 2; ++half) {
        // stage q-half into xsA and k-half into xsB (all 512 threads; 2 float4 each per buffer)
#pragma unroll
        for (int r = 0; r < 2; ++r) {
            int t4 = r * 512 + t;           // 0..1023 = n*32 + c
            int n = t4 >> 5, c = t4 & 31;
            dA[t4] = sq[n * 64 + half * 32 + c];
            dB[t4] = sk[n * 64 + half * 32 + c];
        }
        __syncthreads();
        project_half<Nt>(Wsel, j, tm, xsel, half * DH, 0, acc);
        __syncthreads();   // readers done before next-half stage overwrites
    }

    // ---- K handoff: group 1 publishes Kacc columns to LDS (aliases dead staging buffers) ----
    if (grp) {
#pragma unroll
        for (int n = 0; n < Nt; ++n) Klds[n][j] = acc[n];   // bank = j&31, 2-way: free
    }
    __syncthreads();

    // ---- scores + softmax (group 0 only; acc == Qacc here) ----
    if (!grp) {
        float sc = 0.f;
#pragma unroll
        for (int n = 0; n < Nt; ++n) {
            float p = acc[n] * Klds[n][j];
#pragma unroll
            for (int off = 16; off >= 1; off >>= 1) p += __shfl_xor(p, off, 64);
            sc = (l == n) ? p : sc;
        }
        sc = sc * pri_s[l];
        if (msks[l] != 0) sc = NEGV;
        float mx = sc;
#pragma unroll
        for (int off = 16; off >= 1; off >>= 1) mx = fmaxf(mx, __shfl_xor(mx, off, 64));
        float ex = expf(sc - mx);
        float sum = ex;
#pragma unroll
        for (int off = 16; off >= 1; off >>= 1) sum += __shfl_xor(sum, off, 64);
        float at = ex / sum;
        attn_s[h][l] = at;
        // attn_flat[(h*B + b)*N + n]
        out[ATTN_BASE + h * (Bt * Nt) + b * Nt + l] = at;
    }
    __syncthreads();   // Klds dead, attn_s visible to all

    // ---- V projection: token-split across groups (grp 0: tokens 0..15, grp 1: 16..31) ----
    const float4* sv = (const float4*)(v + (size_t)b * (Nt * Dm));
    unsigned tmv[4];
#pragma unroll
    for (int e = 0; e < 4; ++e) tmv[e] = grp ? (tm[e] >> 16) : (tm[e] & 0xFFFFu);
    const int tokbase = grp ? 16 : 0;

    float vacc[16];
#pragma unroll
    for (int n = 0; n < 16; ++n) vacc[n] = 0.f;

#pragma unroll
    for (int half = 0; half < 2; ++half) {
        // stage v half into xsA region (16 KB; 2 float4 per thread)
#pragma unroll
        for (int r = 0; r < 2; ++r) {
            int t4 = r * 512 + t;
            int n = t4 >> 5, c = t4 & 31;
            dA[t4] = sv[n * 64 + half * 32 + c];
        }
        __syncthreads();
        project_half<16>(Wv, j, tmv, xsA, half * DH, tokbase, vacc);
        __syncthreads();
    }

    // ---- attention output (partial per group): o[j] = sum_n attn[h][n] * V[n][j] ----
    float o = 0.f;
#pragma unroll
    for (int n = 0; n < 16; ++n) o = fmaf(attn_s[h][tokbase + n], vacc[n], o);
    outbuf[grp][j] = o;
    __syncthreads();

    // ---- fc: i-range split across groups; proj[j] = fc_b[ut][j] + sum_i out[i] * fc_w[ut][i][j] ----
    const float* Wf = fc_w + ut * (Dm * Dm) + j;
    float pj = grp ? 0.f : fc_b[ut * Dm + j];
    {
        const int ibase = grp * 128;
        for (int i0 = 0; i0 < 128; i0 += 4) {
            float4 a0 = *(const float4*)&outbuf[0][ibase + i0];
            float4 a1 = *(const float4*)&outbuf[1][ibase + i0];
            pj = fmaf(a0.x + a1.x, Wf[(ibase + i0 + 0) * Dm], pj);
            pj = fmaf(a0.y + a1.y, Wf[(ibase + i0 + 1) * Dm], pj);
            pj = fmaf(a0.z + a1.z, Wf[(ibase + i0 + 2) * Dm], pj);
            pj = fmaf(a0.w + a1.w, Wf[(ibase + i0 + 3) * Dm], pj);
        }
    }
    fcpart[grp][j] = pj;
    __syncthreads();

    // ---- LayerNorm over 256 columns (group 0; reduction across its 4 waves) ----
    float pjf = 0.f;
    if (!grp) {
        pjf = fcpart[0][j] + fcpart[1][j];
        float s1 = pjf, s2 = pjf * pjf;
#pragma unroll
        for (int off = 32; off >= 1; off >>= 1) {
            s1 += __shfl_xor(s1, off, 64);
            s2 += __shfl_xor(s2, off, 64);
        }
        const int w = j >> 6;
        if ((j & 63) == 0) { redA[w] = s1; redB[w] = s2; }
    }
    __syncthreads();
    if (!grp) {
        float t1 = redA[0] + redA[1] + redA[2] + redA[3];
        float t2 = redB[0] + redB[1] + redB[2] + redB[3];
        float mu = t1 * (1.f / 256.f);
        float var = t2 * (1.f / 256.f) - mu * mu;
        float inv = rsqrtf(var + 1e-5f);
        out[b * Dm + j] = (pjf - mu) * inv * gamma[j] + beta[j];
    }
}

extern "C" void kernel_launch(void* const* d_in, const int* in_sizes, int n_in,
                              void* d_out, int out_size, void* d_ws, size_t ws_size,
                              hipStream_t stream) {
    const float* q       = (const float*)d_in[0];
    const float* k       = (const float*)d_in[1];
    const float* v       = (const float*)d_in[2];
    const float* Wq      = (const float*)d_in[3];
    const float* Wk      = (const float*)d_in[4];
    const float* Wv      = (const float*)d_in[5];
    const float* rel_pri = (const float*)d_in[6];
    const float* fc_w    = (const float*)d_in[7];
    const float* fc_b    = (const float*)d_in[8];
    const float* gamma   = (const float*)d_in[9];
    const float* beta    = (const float*)d_in[10];
    const int* seq_etype = (const int*)d_in[11];
    const int* seq_utype = (const int*)d_in[12];
    const int* mask      = (const int*)d_in[13];
    float* outp = (float*)d_out;

    mha_fused_kernel<<<Bt, 512, 0, stream>>>(q, k, v, Wq, Wk, Wv, rel_pri,
                                             fc_w, fc_b, gamma, beta,
                                             seq_etype, seq_utype, mask, outp);
}